// Round 1
// baseline (326.256 us; speedup 1.0000x reference)
//
#include <hip/hip_runtime.h>
#include <hip/hip_bf16.h>
#include <stdint.h>

// ---------- types ----------
typedef __bf16 bf16x8 __attribute__((ext_vector_type(8)));
typedef float  f32x4  __attribute__((ext_vector_type(4)));

__device__ __forceinline__ unsigned short f2bf(float x) {
    union { float f; unsigned u; } v; v.f = x;
    unsigned r = v.u + 0x7fffu + ((v.u >> 16) & 1u);   // RNE
    return (unsigned short)(r >> 16);
}

__device__ __forceinline__ void async16(const void* g, void* l) {
    __builtin_amdgcn_global_load_lds(
        (const __attribute__((address_space(1))) void*)g,
        (__attribute__((address_space(3))) void*)l,
        16, 0, 0);
}

// ---------- generic bf16 B^T GEMM, 128x128 tile, BK=32, 4 waves ----------
// A: M x K (row-major, bf16 bits), Bt: N x K (row-major, bf16 bits)
// C[m][n] = scale * sum_k A[m][k] * Bt[n][k]
// OutT: unsigned short (bf16 bits) or float.
template <typename OutT, bool CAUSAL_SKIP, bool KLIMIT>
__global__ __launch_bounds__(256) void gemm_bt(
    const unsigned short* __restrict__ A,
    const unsigned short* __restrict__ Bt,
    OutT* __restrict__ C,
    int M, int N, int K, int lda, int ldb, int ldc,
    long long sA, long long sB, long long sC, float scale)
{
    const int bn = blockIdx.x, bm = blockIdx.y, bz = blockIdx.z;
    if (CAUSAL_SKIP && bn > bm) return;

    A  += (long long)bz * sA;
    Bt += (long long)bz * sB;
    C  += (long long)bz * sC;

    const int m0 = bm * 128, n0 = bn * 128;
    const int Keff = KLIMIT ? min(K, (bm + 1) * 128) : K;

    __shared__ __align__(16) unsigned short As[128 * 32];
    __shared__ __align__(16) unsigned short Bs[128 * 32];

    const int tid  = threadIdx.x;
    const int w    = tid >> 6, l = tid & 63;
    const int wr   = w >> 1,  wc = w & 1;
    const int lrow = l & 15,  quad = l >> 4;

    f32x4 acc[4][4] = {};

    // staging: chunk c = 2w+j covers rows 16c..16c+15 (row = 16c + l/4, 8 elems at (l%3)*8)
    const int rA0  = 32 * w + (l >> 2);
    const int cOff = (l & 3) * 8;
    const unsigned short* aG0 = A  + (long long)(m0 + rA0)      * lda + cOff;
    const unsigned short* aG1 = A  + (long long)(m0 + rA0 + 16) * lda + cOff;
    const unsigned short* bG0 = Bt + (long long)(n0 + rA0)      * ldb + cOff;
    const unsigned short* bG1 = Bt + (long long)(n0 + rA0 + 16) * ldb + cOff;
    unsigned short* aL0 = &As[(2 * w) * 512 + l * 8];
    unsigned short* aL1 = aL0 + 512;
    unsigned short* bL0 = &Bs[(2 * w) * 512 + l * 8];
    unsigned short* bL1 = bL0 + 512;

    for (int k0 = 0; k0 < Keff; k0 += 32) {
        async16(aG0 + k0, aL0);
        async16(aG1 + k0, aL1);
        async16(bG0 + k0, bL0);
        async16(bG1 + k0, bL1);
        __syncthreads();

        bf16x8 af[4], bfr[4];
#pragma unroll
        for (int i = 0; i < 4; i++) {
            af[i]  = *(const bf16x8*)&As[(wr * 64 + i * 16 + lrow) * 32 + quad * 8];
            bfr[i] = *(const bf16x8*)&Bs[(wc * 64 + i * 16 + lrow) * 32 + quad * 8];
        }
#pragma unroll
        for (int i = 0; i < 4; i++)
#pragma unroll
            for (int j = 0; j < 4; j++)
                acc[i][j] = __builtin_amdgcn_mfma_f32_16x16x32_bf16(af[i], bfr[j], acc[i][j], 0, 0, 0);
        __syncthreads();
    }

    // epilogue: D row = quad*4 + r, col = lrow
#pragma unroll
    for (int i = 0; i < 4; i++) {
        const int m = m0 + wr * 64 + i * 16 + quad * 4;
#pragma unroll
        for (int j = 0; j < 4; j++) {
            const int n = n0 + wc * 64 + j * 16 + lrow;
            OutT* cp = C + (long long)m * ldc + n;
#pragma unroll
            for (int r = 0; r < 4; r++) {
                const float v = acc[i][j][r] * scale;
                if constexpr (sizeof(OutT) == 2)
                    cp[(long long)r * ldc] = (OutT)f2bf(v);
                else
                    cp[(long long)r * ldc] = (OutT)v;
            }
        }
    }
}

// ---------- fp32 -> bf16 cast (vectorized) ----------
__global__ __launch_bounds__(256) void cast_f32_bf16(
    const float4* __restrict__ in, unsigned short* __restrict__ out, int n4)
{
    int i = blockIdx.x * 256 + threadIdx.x;
    if (i >= n4) return;
    float4 v = in[i];
    union { unsigned short u[4]; uint2 p; } o;
    o.u[0] = f2bf(v.x); o.u[1] = f2bf(v.y); o.u[2] = f2bf(v.z); o.u[3] = f2bf(v.w);
    *(uint2*)(out + (long long)i * 4) = o.p;
}

// ---------- W (KxN fp32) -> W^T (NxK bf16), tiled ----------
__global__ __launch_bounds__(256) void transpose_cast_w(
    const float* __restrict__ in, unsigned short* __restrict__ out, int n)
{
    __shared__ float tile[32][33];
    const int tx = threadIdx.x, ty = threadIdx.y;
    const int c0 = blockIdx.x * 32, r0 = blockIdx.y * 32;
#pragma unroll
    for (int i = 0; i < 4; i++)
        tile[ty + i * 8][tx] = in[(long long)(r0 + ty + i * 8) * n + c0 + tx];
    __syncthreads();
#pragma unroll
    for (int i = 0; i < 4; i++)
        out[(long long)(c0 + ty + i * 8) * n + r0 + tx] = f2bf(tile[tx][ty + i * 8]);
}

// ---------- bf16 transpose (R x Cc -> Cc x R), batched over z ----------
__global__ __launch_bounds__(256) void transpose_bf16_k(
    const unsigned short* __restrict__ in, unsigned short* __restrict__ out, int R, int Cc)
{
    const long long zb = (long long)blockIdx.z * R * Cc;
    in += zb; out += zb;
    __shared__ unsigned short tile[32][33];
    const int tx = threadIdx.x, ty = threadIdx.y;
    const int c0 = blockIdx.x * 32, r0 = blockIdx.y * 32;
#pragma unroll
    for (int i = 0; i < 4; i++)
        tile[ty + i * 8][tx] = in[(long long)(r0 + ty + i * 8) * Cc + c0 + tx];
    __syncthreads();
#pragma unroll
    for (int i = 0; i < 4; i++)
        out[(long long)(c0 + ty + i * 8) * R + r0 + tx] = tile[tx][ty + i * 8];
}

// ---------- causal softmax: S (fp32, B*T rows of T) -> P (bf16) ----------
__global__ __launch_bounds__(256) void causal_softmax(
    const float* __restrict__ S, unsigned short* __restrict__ P, int T)
{
    const int row = blockIdx.x;            // 0 .. B*T-1
    const int t   = row & (T - 1);
    const float* s = S + (long long)row * T;
    unsigned short* p = P + (long long)row * T;
    const int L = t + 1;
    const int tid = threadIdx.x;

    float v[8];
    float mx = -3.0e38f;
#pragma unroll
    for (int k = 0; k < 8; k++) {
        const int j = tid + k * 256;
        v[k] = (j < L) ? s[j] : -3.0e38f;
        mx = fmaxf(mx, v[k]);
    }
#pragma unroll
    for (int off = 32; off; off >>= 1) mx = fmaxf(mx, __shfl_xor(mx, off));
    __shared__ float red[4], red2[4];
    const int wid = tid >> 6, lid = tid & 63;
    if (lid == 0) red[wid] = mx;
    __syncthreads();
    mx = fmaxf(fmaxf(red[0], red[1]), fmaxf(red[2], red[3]));

    float sum = 0.f;
#pragma unroll
    for (int k = 0; k < 8; k++) { v[k] = __expf(v[k] - mx); sum += v[k]; }
#pragma unroll
    for (int off = 32; off; off >>= 1) sum += __shfl_xor(sum, off);
    if (lid == 0) red2[wid] = sum;
    __syncthreads();
    sum = red2[0] + red2[1] + red2[2] + red2[3];
    const float inv = 1.0f / sum;
#pragma unroll
    for (int k = 0; k < 8; k++) {
        const int j = tid + k * 256;
        p[j] = f2bf(v[k] * inv);          // exp(-huge)=0 for masked lanes
    }
}

// ---------- launch ----------
extern "C" void kernel_launch(void* const* d_in, const int* in_sizes, int n_in,
                              void* d_out, int out_size, void* d_ws, size_t ws_size,
                              hipStream_t stream)
{
    const int B = 4, T = 2048, C = 1024, D = 1024;
    const float* x  = (const float*)d_in[0];
    const float* Wq = (const float*)d_in[1];
    const float* Wk = (const float*)d_in[2];
    const float* Wv = (const float*)d_in[3];
    float* out = (float*)d_out;
    char* ws = (char*)d_ws;

    const size_t MB = 1ull << 20;
    unsigned short* Xbf = (unsigned short*)(ws + 0);        // 16 MB
    unsigned short* WqT = (unsigned short*)(ws + 16 * MB);  //  2 MB
    unsigned short* WkT = WqT + 1024 * 1024;
    unsigned short* WvT = WkT + 1024 * 1024;
    unsigned short* Q   = (unsigned short*)(ws + 22 * MB);  // 16 MB
    unsigned short* Kb  = (unsigned short*)(ws + 38 * MB);  // 16 MB
    unsigned short* V   = (unsigned short*)(ws + 54 * MB);  // 16 MB
    unsigned short* Vt  = (unsigned short*)(ws + 70 * MB);  // 16 MB
    float*          S   = (float*)(ws + 86 * MB);           // 64 MB
    unsigned short* P   = (unsigned short*)(ws + 0);        // 32 MB (over dead Xbf/WT/Q)

    // 1) x -> bf16
    {
        int n4 = B * T * C / 4;  // 2M
        cast_f32_bf16<<<dim3((n4 + 255) / 256), dim3(256), 0, stream>>>(
            (const float4*)x, Xbf, n4);
    }
    // 2) W^T casts
    {
        dim3 g(32, 32), b(32, 8);
        transpose_cast_w<<<g, b, 0, stream>>>(Wq, WqT, 1024);
        transpose_cast_w<<<g, b, 0, stream>>>(Wk, WkT, 1024);
        transpose_cast_w<<<g, b, 0, stream>>>(Wv, WvT, 1024);
    }
    // 3) Q, K, V GEMMs: per batch M=2048, N=1024, K=1024
    {
        dim3 g(1024 / 128, 2048 / 128, 4), b(256);
        long long sX = (long long)T * C, sO = (long long)T * D;
        gemm_bt<unsigned short, false, false><<<g, b, 0, stream>>>(
            Xbf, WqT, Q,  2048, 1024, 1024, 1024, 1024, 1024, sX, 0, sO, 1.0f);
        gemm_bt<unsigned short, false, false><<<g, b, 0, stream>>>(
            Xbf, WkT, Kb, 2048, 1024, 1024, 1024, 1024, 1024, sX, 0, sO, 1.0f);
        gemm_bt<unsigned short, false, false><<<g, b, 0, stream>>>(
            Xbf, WvT, V,  2048, 1024, 1024, 1024, 1024, 1024, sX, 0, sO, 1.0f);
    }
    // 4) V -> V^T (per batch 2048x1024 -> 1024x2048)
    {
        dim3 g(1024 / 32, 2048 / 32, 4), b(32, 8);
        transpose_bf16_k<<<g, b, 0, stream>>>(V, Vt, 2048, 1024);
    }
    // 5) S = Q K^T / 32, causal lower blocks only
    {
        dim3 g(2048 / 128, 2048 / 128, 4), b(256);
        long long sQ = (long long)T * D, sS = (long long)T * T;
        gemm_bt<float, true, false><<<g, b, 0, stream>>>(
            Q, Kb, S, 2048, 2048, 1024, 1024, 1024, 2048, sQ, sQ, sS, 0.03125f);
    }
    // 6) causal softmax -> P (bf16)
    {
        causal_softmax<<<dim3(B * T), dim3(256), 0, stream>>>(S, P, T);
    }
    // 7) O = P V  (K clamped causally per row-block), fp32 out
    {
        dim3 g(1024 / 128, 2048 / 128, 4), b(256);
        long long sP = (long long)T * T, sV = (long long)D * T, sO = (long long)T * D;
        gemm_bt<float, false, true><<<g, b, 0, stream>>>(
            P, Vt, out, 2048, 1024, 2048, 2048, 2048, 1024, sP, sV, sO, 1.0f);
    }
    (void)in_sizes; (void)n_in; (void)out_size; (void)ws_size;
}

// Round 2
// 295.816 us; speedup vs baseline: 1.1029x; 1.1029x over previous
//
#include <hip/hip_runtime.h>
#include <hip/hip_bf16.h>
#include <stdint.h>

// ---------- types ----------
typedef __bf16 bf16x8 __attribute__((ext_vector_type(8)));
typedef float  f32x4  __attribute__((ext_vector_type(4)));

__device__ __forceinline__ unsigned short f2bf(float x) {
    union { float f; unsigned u; } v; v.f = x;
    unsigned r = v.u + 0x7fffu + ((v.u >> 16) & 1u);   // RNE
    return (unsigned short)(r >> 16);
}

__device__ __forceinline__ void async16(const void* g, void* l) {
    __builtin_amdgcn_global_load_lds(
        (const __attribute__((address_space(1))) void*)g,
        (__attribute__((address_space(3))) void*)l,
        16, 0, 0);
}

// ---------- generic bf16 B^T GEMM, 128x128 tile, BK=32, 4 waves ----------
// A: M x K (row-major, bf16 bits, leading dim lda), Bt: N x K (row-major, ldb)
// C[m][n] = scale * sum_k A[m][k] * Bt[n][k]
template <typename OutT, bool CAUSAL_SKIP, bool KLIMIT>
__global__ __launch_bounds__(256) void gemm_bt(
    const unsigned short* __restrict__ A,
    const unsigned short* __restrict__ Bt,
    OutT* __restrict__ C,
    int M, int N, int K, int lda, int ldb, int ldc,
    long long sA, long long sB, long long sC, float scale)
{
    const int bn = blockIdx.x, bm = blockIdx.y, bz = blockIdx.z;
    if (CAUSAL_SKIP && bn > bm) return;

    A  += (long long)bz * sA;
    Bt += (long long)bz * sB;
    C  += (long long)bz * sC;

    const int m0 = bm * 128, n0 = bn * 128;
    const int Keff = KLIMIT ? min(K, (bm + 1) * 128) : K;

    __shared__ __align__(16) unsigned short As[128 * 32];
    __shared__ __align__(16) unsigned short Bs[128 * 32];

    const int tid  = threadIdx.x;
    const int w    = tid >> 6, l = tid & 63;
    const int wr   = w >> 1,  wc = w & 1;
    const int lrow = l & 15,  quad = l >> 4;

    f32x4 acc[4][4] = {};

    const int rA0  = 32 * w + (l >> 2);
    const int cOff = (l & 3) * 8;
    const unsigned short* aG0 = A  + (long long)(m0 + rA0)      * lda + cOff;
    const unsigned short* aG1 = A  + (long long)(m0 + rA0 + 16) * lda + cOff;
    const unsigned short* bG0 = Bt + (long long)(n0 + rA0)      * ldb + cOff;
    const unsigned short* bG1 = Bt + (long long)(n0 + rA0 + 16) * ldb + cOff;
    unsigned short* aL0 = &As[(2 * w) * 512 + l * 8];
    unsigned short* aL1 = aL0 + 512;
    unsigned short* bL0 = &Bs[(2 * w) * 512 + l * 8];
    unsigned short* bL1 = bL0 + 512;

    for (int k0 = 0; k0 < Keff; k0 += 32) {
        async16(aG0 + k0, aL0);
        async16(aG1 + k0, aL1);
        async16(bG0 + k0, bL0);
        async16(bG1 + k0, bL1);
        __syncthreads();

        bf16x8 af[4], bfr[4];
#pragma unroll
        for (int i = 0; i < 4; i++) {
            af[i]  = *(const bf16x8*)&As[(wr * 64 + i * 16 + lrow) * 32 + quad * 8];
            bfr[i] = *(const bf16x8*)&Bs[(wc * 64 + i * 16 + lrow) * 32 + quad * 8];
        }
#pragma unroll
        for (int i = 0; i < 4; i++)
#pragma unroll
            for (int j = 0; j < 4; j++)
                acc[i][j] = __builtin_amdgcn_mfma_f32_16x16x32_bf16(af[i], bfr[j], acc[i][j], 0, 0, 0);
        __syncthreads();
    }

    // epilogue: D row = quad*4 + r, col = lrow
#pragma unroll
    for (int i = 0; i < 4; i++) {
        const int m = m0 + wr * 64 + i * 16 + quad * 4;
#pragma unroll
        for (int j = 0; j < 4; j++) {
            const int n = n0 + wc * 64 + j * 16 + lrow;
            OutT* cp = C + (long long)m * ldc + n;
#pragma unroll
            for (int r = 0; r < 4; r++) {
                const float v = acc[i][j][r] * scale;
                if constexpr (sizeof(OutT) == 2)
                    cp[(long long)r * ldc] = (OutT)f2bf(v);
                else
                    cp[(long long)r * ldc] = (OutT)v;
            }
        }
    }
}

// ---------- fp32 -> bf16 cast (vectorized) ----------
__global__ __launch_bounds__(256) void cast_f32_bf16(
    const float4* __restrict__ in, unsigned short* __restrict__ out, int n4)
{
    int i = blockIdx.x * 256 + threadIdx.x;
    if (i >= n4) return;
    float4 v = in[i];
    union { unsigned short u[4]; uint2 p; } o;
    o.u[0] = f2bf(v.x); o.u[1] = f2bf(v.y); o.u[2] = f2bf(v.z); o.u[3] = f2bf(v.w);
    *(uint2*)(out + (long long)i * 4) = o.p;
}

// ---------- fused W_{q,k,v} (1024x1024 fp32) -> concatenated W^T (3*1024 x 1024 bf16) ----------
__global__ __launch_bounds__(256) void transpose_cast_w3(
    const float* __restrict__ W0, const float* __restrict__ W1,
    const float* __restrict__ W2, unsigned short* __restrict__ out, int n)
{
    const float* in = (blockIdx.z == 0) ? W0 : (blockIdx.z == 1) ? W1 : W2;
    out += (long long)blockIdx.z * n * n;
    __shared__ float tile[32][33];
    const int tx = threadIdx.x, ty = threadIdx.y;
    const int c0 = blockIdx.x * 32, r0 = blockIdx.y * 32;
#pragma unroll
    for (int i = 0; i < 4; i++)
        tile[ty + i * 8][tx] = in[(long long)(r0 + ty + i * 8) * n + c0 + tx];
    __syncthreads();
#pragma unroll
    for (int i = 0; i < 4; i++)
        out[(long long)(c0 + ty + i * 8) * n + r0 + tx] = f2bf(tile[tx][ty + i * 8]);
}

// ---------- bf16 strided transpose, batched over z: out[c][r] = in[r][c] ----------
__global__ __launch_bounds__(256) void transpose_bf16_k(
    const unsigned short* __restrict__ in, unsigned short* __restrict__ out,
    int ldin, int ldout, long long sin, long long sout)
{
    in  += (long long)blockIdx.z * sin;
    out += (long long)blockIdx.z * sout;
    __shared__ unsigned short tile[32][33];
    const int tx = threadIdx.x, ty = threadIdx.y;
    const int c0 = blockIdx.x * 32, r0 = blockIdx.y * 32;
#pragma unroll
    for (int i = 0; i < 4; i++)
        tile[ty + i * 8][tx] = in[(long long)(r0 + ty + i * 8) * ldin + c0 + tx];
    __syncthreads();
#pragma unroll
    for (int i = 0; i < 4; i++)
        out[(long long)(c0 + ty + i * 8) * ldout + r0 + tx] = tile[tx][ty + i * 8];
}

// ---------- causal softmax: S (fp32, B*T rows of T) -> P (bf16) ----------
__global__ __launch_bounds__(256) void causal_softmax(
    const float* __restrict__ S, unsigned short* __restrict__ P, int T)
{
    const int row = blockIdx.x;            // 0 .. B*T-1
    const int t   = row & (T - 1);
    const float* s = S + (long long)row * T;
    unsigned short* p = P + (long long)row * T;
    const int L = t + 1;
    const int tid = threadIdx.x;

    float v[8];
    float mx = -3.0e38f;
#pragma unroll
    for (int k = 0; k < 8; k++) {
        const int j = tid + k * 256;
        v[k] = (j < L) ? s[j] : -3.0e38f;
        mx = fmaxf(mx, v[k]);
    }
#pragma unroll
    for (int off = 32; off; off >>= 1) mx = fmaxf(mx, __shfl_xor(mx, off));
    __shared__ float red[4], red2[4];
    const int wid = tid >> 6, lid = tid & 63;
    if (lid == 0) red[wid] = mx;
    __syncthreads();
    mx = fmaxf(fmaxf(red[0], red[1]), fmaxf(red[2], red[3]));

    float sum = 0.f;
#pragma unroll
    for (int k = 0; k < 8; k++) { v[k] = __expf(v[k] - mx); sum += v[k]; }
#pragma unroll
    for (int off = 32; off; off >>= 1) sum += __shfl_xor(sum, off);
    if (lid == 0) red2[wid] = sum;
    __syncthreads();
    sum = red2[0] + red2[1] + red2[2] + red2[3];
    const float inv = 1.0f / sum;
#pragma unroll
    for (int k = 0; k < 8; k++) {
        const int j = tid + k * 256;
        p[j] = f2bf(v[k] * inv);          // exp(-huge)=0 for masked lanes
    }
}

// ---------- launch ----------
extern "C" void kernel_launch(void* const* d_in, const int* in_sizes, int n_in,
                              void* d_out, int out_size, void* d_ws, size_t ws_size,
                              hipStream_t stream)
{
    const int B = 4, T = 2048, C = 1024, D = 1024;
    const float* x  = (const float*)d_in[0];
    const float* Wq = (const float*)d_in[1];
    const float* Wk = (const float*)d_in[2];
    const float* Wv = (const float*)d_in[3];
    float* out = (float*)d_out;
    char* ws = (char*)d_ws;

    const size_t MB = 1ull << 20;
    // layout (peak 150 MB, proven in R1):
    //  0..16   Xbf (bf16 x)                [dead after QKV gemm]
    // 16..22   WqkvT (3072x1024 bf16)      [dead after QKV gemm]
    // 22..70   QKV (4 x 2048 x 3072 bf16)  [dead after Vt + S]
    // 70..86   Vt  (4 x 1024 x 2048 bf16)
    // 86..150  S   (4 x 2048 x 2048 fp32)
    //  0..32   P   (4 x 2048 x 2048 bf16)  [overlays Xbf/WqkvT/QKV-head, all dead by then]
    unsigned short* Xbf   = (unsigned short*)(ws + 0);
    unsigned short* WqkvT = (unsigned short*)(ws + 16 * MB);
    unsigned short* QKV   = (unsigned short*)(ws + 22 * MB);
    unsigned short* Vt    = (unsigned short*)(ws + 70 * MB);
    float*          S     = (float*)(ws + 86 * MB);
    unsigned short* P     = (unsigned short*)(ws + 0);

    const long long sX   = (long long)T * C;       // 2048*1024
    const long long sQKV = (long long)T * 3 * D;   // 2048*3072
    const long long sVt  = (long long)D * T;       // 1024*2048
    const long long sS   = (long long)T * T;       // 2048*2048
    const long long sO   = (long long)T * D;       // 2048*1024

    // 1) x -> bf16
    {
        int n4 = B * T * C / 4;
        cast_f32_bf16<<<dim3((n4 + 255) / 256), dim3(256), 0, stream>>>(
            (const float4*)x, Xbf, n4);
    }
    // 2) fused W^T cast: WqkvT rows [0,1024)=Wq^T, [1024,2048)=Wk^T, [2048,3072)=Wv^T
    {
        dim3 g(32, 32, 3), b(32, 8);
        transpose_cast_w3<<<g, b, 0, stream>>>(Wq, Wk, Wv, WqkvT, 1024);
    }
    // 3) fused QKV GEMM: per batch M=2048, N=3072, K=1024 -> QKV row-interleaved
    {
        dim3 g(3072 / 128, 2048 / 128, 4), b(256);
        gemm_bt<unsigned short, false, false><<<g, b, 0, stream>>>(
            Xbf, WqkvT, QKV, 2048, 3072, 1024, 1024, 1024, 3072, sX, 0, sQKV, 1.0f);
    }
    // 4) V (cols 2048..3071 of QKV) -> V^T (1024 x 2048 per batch)
    {
        dim3 g(1024 / 32, 2048 / 32, 4), b(32, 8);
        transpose_bf16_k<<<g, b, 0, stream>>>(
            QKV + 2 * D, Vt, 3 * D, T, sQKV, sVt);
    }
    // 5) S = Q K^T / 32, causal lower blocks only (Q,K strided views of QKV)
    {
        dim3 g(2048 / 128, 2048 / 128, 4), b(256);
        gemm_bt<float, true, false><<<g, b, 0, stream>>>(
            QKV, QKV + D, S, 2048, 2048, 1024, 3 * D, 3 * D, 2048, sQKV, sQKV, sS, 0.03125f);
    }
    // 6) causal softmax -> P (bf16)
    {
        causal_softmax<<<dim3(B * T), dim3(256), 0, stream>>>(S, P, T);
    }
    // 7) O = P V (K clamped causally per row-block), fp32 out
    {
        dim3 g(1024 / 128, 2048 / 128, 4), b(256);
        gemm_bt<float, false, true><<<g, b, 0, stream>>>(
            P, Vt, out, 2048, 1024, 2048, 2048, 2048, 1024, sS, sVt, sO, 1.0f);
    }
    (void)in_sizes; (void)n_in; (void)out_size; (void)ws_size;
}